// Round 22
// baseline (66.333 us; speedup 1.0000x reference)
//
#include <hip/hip_runtime.h>
#include <hip/hip_fp16.h>

typedef _Float16 h16;
typedef __attribute__((ext_vector_type(4))) _Float16 h16x4;
typedef __attribute__((ext_vector_type(8))) _Float16 h16x8;
typedef __attribute__((ext_vector_type(4))) float f32x4;

#define DIM   1024
#define SEQ   2048
#define NKV   2
#define HD    64
#define HALFW 128
#define NQKV  1280
#define SPAD  2304            // padded seq: 128 + 2048 + 128
#define KPS   (SPAD*HD)       // 147456 h16 per [b][g] slab
#define KSTG  288             // staged key rows per 32-query block
#define VSTR  312             // Vts row stride (2-way-conflict-free)
#define PSTR  296             // P row stride (2-way-conflict-free)
#define LOG2E 1.4426950408889634f

// ---------------- fused preprocess (r21, unchanged) ----------------
// [0,2048): x fp32->fp16 (+bias concat, bq*log2e)
// [2048,3328): Wq|Wk|Wv transpose -> wqkvt (Wq part * log2e)
// [3328,4352): Wo transpose -> wot
// [4352,4480): zero-fill pad regions of k_pad AND vt_pad
__global__ void preprocess_kernel(const float* __restrict__ x,
                                  const float* __restrict__ bq,
                                  const float* __restrict__ bk,
                                  const float* __restrict__ bv,
                                  const float* __restrict__ Wq,
                                  const float* __restrict__ Wk,
                                  const float* __restrict__ Wv,
                                  const float* __restrict__ Wo,
                                  h16* __restrict__ xh, float* __restrict__ bqkv,
                                  h16* __restrict__ wqkvt, h16* __restrict__ wot,
                                  h16* __restrict__ kpad, h16* __restrict__ vtpad)
{
    __shared__ float tile[32][33];
    const int tid = threadIdx.x;
    const int blk = blockIdx.x;
    if (blk < 2048) {
        int i = blk * 256 + tid;
        size_t base = (size_t)i * 8;
        float4 a = *(const float4*)(x + base);
        float4 b = *(const float4*)(x + base + 4);
        h16x8 o = { (h16)a.x,(h16)a.y,(h16)a.z,(h16)a.w,
                    (h16)b.x,(h16)b.y,(h16)b.z,(h16)b.w };
        *(h16x8*)(xh + base) = o;
        if (i < NQKV) {
            float v = (i < DIM) ? bq[i] * LOG2E
                                : (i < DIM+128 ? bk[i-DIM] : bv[i-DIM-128]);
            bqkv[i] = v;
        }
        return;
    }
    if (blk >= 4352) {                       // pad fill: 128 blocks
        int idx = (blk - 4352) * 256 + tid;  // 0..32767
        h16x8 z8 = {};
        h16* dstb = (idx < 16384) ? kpad : vtpad;
        int i2 = idx & 16383;
        int bg = i2 >> 12, j = i2 & 4095;
        if (j < 2048) {
            size_t off;
            if (idx < 16384) {               // kpad: rows 0..127 then 2176..2303
                off = (j < 1024) ? (size_t)j*8 : (size_t)2176*HD + (size_t)(j-1024)*8;
            } else {                         // vtpad: per d, cols [0,128)+[2176,2304)
                int d = j >> 5, r = j & 31;
                off = (size_t)d*SPAD + ((r & 16) ? 2176 : 0) + (size_t)(r & 15)*8;
            }
            *(h16x8*)(dstb + (size_t)bg*KPS + off) = z8;
        }
        return;
    }
    const int tx = tid & 31, ty = tid >> 5;
    if (blk < 2048 + 1280) {
        int bid = blk - 2048;
        int n0 = (bid % 40) * 32, k0 = (bid / 40) * 32;
        const float* src; int ldn, noff; float scl;
        if (n0 < DIM)          { src = Wq; ldn = DIM; noff = n0; scl = LOG2E; }
        else if (n0 < DIM+128) { src = Wk; ldn = 128; noff = n0 - DIM; scl = 1.f; }
        else                   { src = Wv; ldn = 128; noff = n0 - DIM - 128; scl = 1.f; }
#pragma unroll
        for (int i = 0; i < 4; ++i)
            tile[ty + 8*i][tx] = src[(size_t)(k0 + ty + 8*i)*ldn + noff + tx] * scl;
        __syncthreads();
#pragma unroll
        for (int i = 0; i < 4; ++i)
            wqkvt[(size_t)(n0 + ty + 8*i)*DIM + k0 + tx] = (h16)tile[tx][ty + 8*i];
    } else {
        int bid = blk - 3328;
        int n0 = (bid % 32) * 32, k0 = (bid / 32) * 32;
#pragma unroll
        for (int i = 0; i < 4; ++i)
            tile[ty + 8*i][tx] = Wo[(size_t)(k0 + ty + 8*i)*DIM + n0 + tx];
        __syncthreads();
#pragma unroll
        for (int i = 0; i < 4; ++i)
            wot[(size_t)(n0 + ty + 8*i)*DIM + k0 + tx] = (h16)tile[tx][ty + 8*i];
    }
}

// ------------- GEMM: 128xBN tile, BK=64, 4 waves, 2-phase counted vmcnt --------
// MODE 0 (BN=160, grid 32x8=256 exact): tiles 0..6 -> q + k scatter;
//   tile 7 (n0=1120) -> k-cols nn[96,128) scalar + ALL v transposed -> vt_pad.
// MODE 1 (BN=128, grid 256): fp32 out + bias.
// Per-wave: 64 m x BN/2 n. NI = BN/32 b-frags. Loads/stage = 4 A + BN/32 B.
template<int MODE, int BN>
__global__ __launch_bounds__(256, 2)
void gemm_kernel(const h16* __restrict__ A, const h16* __restrict__ Bt,
                 const float* __restrict__ bias,
                 h16* __restrict__ qo, h16* __restrict__ ko, h16* __restrict__ vo,
                 float* __restrict__ co, int K, int nx)
{
    constexpr int NI   = BN / 32;                 // b-frags per wave (5 or 4)
    constexpr int BUFSZ = (128 + BN) * 64;        // h16 per buffer
    constexpr int NLD  = 4 + BN/32;               // loads per stage per thread
    extern __shared__ __align__(16) h16 lds[];    // 2 * BUFSZ
    const int nwg = gridDim.x, bid = blockIdx.x;
    const int wg = (bid & 7) * (nwg >> 3) + (bid >> 3);   // XCD swizzle (nwg%8==0)
    const int m0 = (wg / nx) * 128, n0 = (wg % nx) * BN;
    const int tid = threadIdx.x, lane = tid & 63, wid = tid >> 6;
    const int wr = wid >> 1, wc = wid & 1;                // 2x2 waves
    f32x4 acc[4][NI] = {};

    auto stage = [&](int buf, int kk) {
        h16* Ab = lds + buf * BUFSZ;
        h16* Bb = Ab + 128*64;
#pragma unroll
        for (int i = 0; i < 4; ++i) {                     // A: 128 rows
            int slot = i*256 + tid;
            int row = slot >> 3;
            int scol = ((slot & 7) ^ (row & 7)) * 8;
            __builtin_amdgcn_global_load_lds(
                (const __attribute__((address_space(1))) void*)(A + (size_t)(m0 + row)*K + kk + scol),
                (__attribute__((address_space(3))) void*)(Ab + slot*8), 16, 0, 0);
        }
#pragma unroll
        for (int i = 0; i < BN/32; ++i) {                 // B: BN rows
            int slot = i*256 + tid;
            int row = slot >> 3;
            int scol = ((slot & 7) ^ (row & 7)) * 8;
            __builtin_amdgcn_global_load_lds(
                (const __attribute__((address_space(1))) void*)(Bt + (size_t)(n0 + row)*K + kk + scol),
                (__attribute__((address_space(3))) void*)(Bb + slot*8), 16, 0, 0);
        }
    };
    auto compute = [&](int buf) {
        const h16* Ab = lds + buf * BUFSZ;
        const h16* Bb = Ab + 128*64;
#pragma unroll
        for (int k2 = 0; k2 < 2; ++k2) {
            h16x8 a[4], b[NI];
#pragma unroll
            for (int mi = 0; mi < 4; ++mi) {
                int row = wr*64 + mi*16 + (lane & 15);
                int cc = (k2*4 + (lane >> 4)) ^ (row & 7);
                a[mi] = *(const h16x8*)(Ab + row*64 + cc*8);
            }
#pragma unroll
            for (int ni = 0; ni < NI; ++ni) {
                int row = wc*(BN/2) + ni*16 + (lane & 15);
                int cc = (k2*4 + (lane >> 4)) ^ (row & 7);
                b[ni] = *(const h16x8*)(Bb + row*64 + cc*8);
            }
#pragma unroll
            for (int mi = 0; mi < 4; ++mi)
#pragma unroll
                for (int ni = 0; ni < NI; ++ni)
                    acc[mi][ni] = __builtin_amdgcn_mfma_f32_16x16x32_f16(a[mi], b[ni], acc[mi][ni], 0, 0, 0);
        }
    };

    const int ns = K >> 6;
    stage(0, 0);
    int cur = 0;
    for (int i = 0; i < ns; ++i) {
        if (i < ns-1) {
            stage(cur ^ 1, (i+1) << 6);
            if constexpr (NLD == 9) asm volatile("s_waitcnt vmcnt(9)" ::: "memory");
            else                    asm volatile("s_waitcnt vmcnt(8)" ::: "memory");
        } else {
            asm volatile("s_waitcnt vmcnt(0)" ::: "memory");
        }
        __builtin_amdgcn_s_barrier();
        __builtin_amdgcn_sched_barrier(0);
        compute(cur);
        if (i < ns-1) {
            __builtin_amdgcn_s_barrier();
            __builtin_amdgcn_sched_barrier(0);
        }
        cur ^= 1;
    }

    if (MODE == 0 && n0 == 1120) {
        // ---- tile 7: k-cols nrel<32 scalar scatter; v (nrel>=32) via transpose ---
        const int bi2 = m0 >> 11, sbase = m0 & 2047;
        if (wc == 0) {                                     // nrel = ni*16+(lane&15) < 32
#pragma unroll
            for (int ni = 0; ni < 2; ++ni) {
                int nrel = ni*16 + (lane & 15);
                int n = 1120 + nrel;                       // nn in [96,128): g=1
                float bv = bias[n];
                int nn = n - DIM, g = nn >> 6, d = nn & 63;
#pragma unroll
                for (int mi = 0; mi < 4; ++mi) {
                    int mb = m0 + wr*64 + mi*16 + (lane >> 4)*4;
#pragma unroll
                    for (int r = 0; r < 4; ++r) {
                        int m = mb + r, s = m & 2047;
                        ko[((size_t)((m >> 11)*NKV + g)*SPAD + s + HALFW)*HD + d]
                            = (h16)(acc[mi][ni][r] + bv);
                    }
                }
            }
        }
        __syncthreads();
        h16* T = lds;                                      // [160][136] = 43.5 KB
#pragma unroll
        for (int ni = 0; ni < NI; ++ni) {
            int nrel = wc*(BN/2) + ni*16 + (lane & 15);
            float bv = bias[1120 + nrel];
#pragma unroll
            for (int mi = 0; mi < 4; ++mi) {
                int mrel = wr*64 + mi*16 + (lane >> 4)*4;
#pragma unroll
                for (int r = 0; r < 4; ++r)
                    T[nrel*136 + mrel + r] = (h16)(acc[mi][ni][r] + bv);
            }
        }
        __syncthreads();
#pragma unroll
        for (int i = 0; i < 8; ++i) {
            int slot = i*256 + tid;                        // 128 v-rows x 16 chunks
            int vrow = slot >> 4, cc = slot & 15;
            int nrel = 32 + vrow;
            int g = vrow >> 6, d = vrow & 63;
            h16x8 val = *(const h16x8*)(T + nrel*136 + cc*8);
            *(h16x8*)(vo + ((size_t)(bi2*NKV + g))*KPS + (size_t)d*SPAD
                      + HALFW + sbase + cc*8) = val;
        }
        return;
    }

#pragma unroll
    for (int ni = 0; ni < NI; ++ni) {
        int n = n0 + wc*(BN/2) + ni*16 + (lane & 15);
        float bv = bias[n];
#pragma unroll
        for (int mi = 0; mi < 4; ++mi) {
            int mb = m0 + wr*64 + mi*16 + (lane >> 4)*4;
#pragma unroll
            for (int r = 0; r < 4; ++r) {
                int m = mb + r;
                float v = acc[mi][ni][r] + bv;
                if (MODE == 1) {
                    co[(size_t)m*DIM + n] = v;
                } else {
                    h16 hv = (h16)v;
                    if (n < DIM) {
                        qo[(size_t)m*DIM + n] = hv;
                    } else {
                        int nn = n - DIM;                  // k region only here
                        int bi2 = m >> 11, s = m & 2047;
                        int g = nn >> 6, d = nn & 63;
                        ko[((size_t)(bi2*NKV + g)*SPAD + s + HALFW)*HD + d] = hv;
                    }
                }
            }
        }
    }
}

// ------------- sliding-window attention (r21, unchanged) -----------------------
__global__ __launch_bounds__(512)
void attn_kernel(const h16* __restrict__ qb, const h16* __restrict__ kpad,
                 const h16* __restrict__ vtpad, h16* __restrict__ ob)
{
    extern __shared__ char smem[];
    h16* Ks  = (h16*)smem;                          // 36864 B
    h16* Vts = (h16*)(smem + 36864);                // 39936 B
    h16* Ps  = (h16*)(smem + 76800);                // 75776 B (total 152576)
    const int tid = threadIdx.x, lane = tid & 63, wid = tid >> 6;
    const int qt = blockIdx.x, g = blockIdx.y, bi = blockIdx.z;
    const int s0 = qt * 32;
    const h16* Kbase = kpad  + (size_t)(bi*NKV + g)*KPS + (size_t)s0*HD;
    const h16* Vbase = vtpad + (size_t)(bi*NKV + g)*KPS + s0;

    for (int slot = tid; slot < KSTG*8; slot += 512) {
        int row = slot >> 3, cc = slot & 7;
        h16x8 val = *(const h16x8*)(Kbase + (size_t)row*HD + cc*8);
        *(h16x8*)(Ks + row*64 + ((cc ^ (row & 7)) * 8)) = val;
    }
    for (int slot = tid; slot < 64*38; slot += 512) {
        int row = slot / 38, cc = slot - row*38;
        h16x8 val = *(const h16x8*)(Vbase + (size_t)row*SPAD + cc*8);
        *(h16x8*)(Vts + row*VSTR + cc*8) = val;
    }
    h16* P = Ps + wid * 16 * PSTR;
    for (int i = lane; i < 256; i += 64)
        P[(i >> 4)*PSTR + 272 + (i & 15)] = (h16)0;
    __syncthreads();

    const int h = g*8 + wid;
    const int colbase = lane & 15;          // query (strip-local)
    const int rowbase = (lane >> 4) * 4;    // key sub-row
    const int kg = rowbase;

    for (int strip = 0; strip < 2; ++strip) {
        const int ss0 = s0 + strip*16;
        h16x8 aq[2];
#pragma unroll
        for (int c = 0; c < 2; ++c)
            aq[c] = *(const h16x8*)(qb + ((size_t)(bi*SEQ + ss0 + colbase))*DIM
                                    + h*HD + c*32 + (lane >> 4)*8);

        f32x4 sc[17];
        __builtin_amdgcn_s_setprio(1);
#pragma unroll
        for (int t = 0; t < 17; ++t) {
            f32x4 z = {0.f,0.f,0.f,0.f};
#pragma unroll
            for (int c = 0; c < 2; ++c) {
                int key = strip*16 + t*16 + colbase;
                h16x8 kf = *(const h16x8*)(Ks + key*64 + (((c*4 + (lane >> 4)) ^ (key & 7)) * 8));
                z = __builtin_amdgcn_mfma_f32_16x16x32_f16(kf, aq[c], z, 0, 0, 0);
            }
            sc[t] = z;
        }
        __builtin_amdgcn_s_setprio(0);

        float mx = -1e30f;
#pragma unroll
        for (int r = 0; r < 4; ++r) {
            float v0  = (kg + r >= colbase) ? sc[0][r]  : -1e30f;
            float v16 = (kg + r <  colbase) ? sc[16][r] : -1e30f;
            sc[0][r] = v0; sc[16][r] = v16;
            mx = fmaxf(mx, fmaxf(v0, v16));
        }
#pragma unroll
        for (int t = 1; t < 16; t += 3) {
#pragma unroll
            for (int r = 0; r < 4; ++r) {
                float a = sc[t][r];
                float b = (t+1 < 16) ? sc[t+1][r] : -1e30f;
                float c2 = (t+2 < 16) ? sc[t+2][r] : -1e30f;
                mx = fmaxf(mx, fmaxf(fmaxf(a, b), c2));
            }
        }
        mx = fmaxf(mx, __shfl_xor(mx, 16));
        mx = fmaxf(mx, __shfl_xor(mx, 32));
        float sum = 0.f;
#pragma unroll
        for (int t = 0; t < 17; ++t)
#pragma unroll
            for (int r = 0; r < 4; ++r) {
                float p = exp2f(sc[t][r] - mx);   // scores pre-scaled by log2e
                sc[t][r] = p;
                sum += p;
            }
        sum += __shfl_xor(sum, 16);
        sum += __shfl_xor(sum, 32);
        float inv = 1.0f / sum;                   // per-query (colbase) inverse

        // write P UNNORMALIZED (p <= 1, h16-safe)
#pragma unroll
        for (int t = 0; t < 17; ++t) {
            h16x4 pk = { (h16)sc[t][0], (h16)sc[t][1],
                         (h16)sc[t][2], (h16)sc[t][3] };
            *(h16x4*)(P + colbase*PSTR + t*16 + kg) = pk;
        }

        f32x4 ao[4] = {};
        __builtin_amdgcn_s_setprio(1);
#pragma unroll
        for (int c = 0; c < 9; ++c) {
            h16x8 pa = *(const h16x8*)(P + colbase*PSTR + c*32 + (lane >> 4)*8);
            int vcol = strip*16 + c*32 + (lane >> 4)*8;
#pragma unroll
            for (int t2 = 0; t2 < 4; ++t2) {
                h16x8 vb = *(const h16x8*)(Vts + (t2*16 + colbase)*VSTR + vcol);
                ao[t2] = __builtin_amdgcn_mfma_f32_16x16x32_f16(pa, vb, ao[t2], 0, 0, 0);
            }
        }
        __builtin_amdgcn_s_setprio(0);

        // epilogue: normalize by the OWNING query's inv (lane qrow has colbase=qrow)
#pragma unroll
        for (int r = 0; r < 4; ++r) {
            int qrow = rowbase + r;
            float iq = __shfl(inv, qrow);
            size_t rowoff = ((size_t)(bi*SEQ + ss0 + qrow))*DIM + h*HD;
#pragma unroll
            for (int t2 = 0; t2 < 4; ++t2)
                ob[rowoff + t2*16 + colbase] = (h16)(ao[t2][r] * iq);
        }
    }
}

extern "C" void kernel_launch(void* const* d_in, const int* in_sizes, int n_in,
                              void* d_out, int out_size, void* d_ws, size_t ws_size,
                              hipStream_t stream)
{
    const float* x  = (const float*)d_in[0];
    const float* Wq = (const float*)d_in[1];
    const float* bq = (const float*)d_in[2];
    const float* Wk = (const float*)d_in[3];
    const float* bk = (const float*)d_in[4];
    const float* Wv = (const float*)d_in[5];
    const float* bv = (const float*)d_in[6];
    const float* Wo = (const float*)d_in[7];
    const float* bo = (const float*)d_in[8];
    float* out = (float*)d_out;
    char* ws = (char*)d_ws;

    h16*   xh    = (h16*)(ws);                 //  x fp16 [4096][1024]
    h16*   wqkvt = (h16*)(ws + 8388608);       //  Wqkv^T [1280][1024]
    h16*   wot   = (h16*)(ws + 11010048);      //  Wo^T [1024][1024]
    float* bqkv  = (float*)(ws + 13107200);
    h16*   q_b   = (h16*)(ws + 13112320);      //  q [4096][1024]
    h16*   k_pad = (h16*)(ws + 21500928);      //  k_pad [b][g][2304][64]
    h16*   vt_pad= (h16*)(ws + 22680576);      //  vt_pad [b][g][64][2304]
    h16*   att_b = (h16*)(ws + 23860224);      //  attn out [4096][1024]

    preprocess_kernel<<<4480, 256, 0, stream>>>(x, bq, bk, bv, Wq, Wk, Wv, Wo,
                                                xh, bqkv, wqkvt, wot, k_pad, vt_pad);
    hipFuncSetAttribute((const void*)(gemm_kernel<0,160>),
                        hipFuncAttributeMaxDynamicSharedMemorySize, 73728);
    gemm_kernel<0,160><<<256, 256, 73728, stream>>>(xh, wqkvt, bqkv,
                                            q_b, k_pad, vt_pad, nullptr, DIM, 8);
    hipFuncSetAttribute((const void*)attn_kernel,
                        hipFuncAttributeMaxDynamicSharedMemorySize, 152576);
    attn_kernel<<<dim3(64, 2, 2), 512, 152576, stream>>>(q_b, k_pad, vt_pad, att_b);
    hipFuncSetAttribute((const void*)(gemm_kernel<1,128>),
                        hipFuncAttributeMaxDynamicSharedMemorySize, 65536);
    gemm_kernel<1,128><<<256, 256, 65536, stream>>>(att_b, wot, bo,
                                            nullptr, nullptr, nullptr, out, DIM, 8);
}

// Round 23
// 63.814 us; speedup vs baseline: 1.0395x; 1.0395x over previous
//
#include <hip/hip_runtime.h>
#include <hip/hip_fp16.h>

typedef _Float16 h16;
typedef __attribute__((ext_vector_type(4))) _Float16 h16x4;
typedef __attribute__((ext_vector_type(8))) _Float16 h16x8;
typedef __attribute__((ext_vector_type(4))) float f32x4;

#define DIM   1024
#define SEQ   2048
#define NKV   2
#define HD    64
#define HALFW 128
#define NQKV  1280
#define SPAD  2304            // padded seq: 128 + 2048 + 128
#define KPS   (SPAD*HD)       // 147456 h16 per [b][g] slab
#define KSTG  288             // staged key rows per 32-query block
#define VSTR  312             // Vts row stride (2-way-conflict-free)
#define PSTR  296             // P row stride (2-way-conflict-free)
#define LOG2E 1.4426950408889634f

// ---------------- fused preprocess ----------------
// [0,2048): x fp32->fp16 (+bias concat, bq*log2e)
// [2048,3328): Wq|Wk|Wv transpose -> wqkvt (Wq part * log2e)
// [3328,4352): Wo transpose -> wot
// [4352,4480): zero-fill pad regions of k_pad AND vt_pad
__global__ void preprocess_kernel(const float* __restrict__ x,
                                  const float* __restrict__ bq,
                                  const float* __restrict__ bk,
                                  const float* __restrict__ bv,
                                  const float* __restrict__ Wq,
                                  const float* __restrict__ Wk,
                                  const float* __restrict__ Wv,
                                  const float* __restrict__ Wo,
                                  h16* __restrict__ xh, float* __restrict__ bqkv,
                                  h16* __restrict__ wqkvt, h16* __restrict__ wot,
                                  h16* __restrict__ kpad, h16* __restrict__ vtpad)
{
    __shared__ float tile[32][33];
    const int tid = threadIdx.x;
    const int blk = blockIdx.x;
    if (blk < 2048) {
        int i = blk * 256 + tid;
        size_t base = (size_t)i * 8;
        float4 a = *(const float4*)(x + base);
        float4 b = *(const float4*)(x + base + 4);
        h16x8 o = { (h16)a.x,(h16)a.y,(h16)a.z,(h16)a.w,
                    (h16)b.x,(h16)b.y,(h16)b.z,(h16)b.w };
        *(h16x8*)(xh + base) = o;
        if (i < NQKV) {
            float v = (i < DIM) ? bq[i] * LOG2E
                                : (i < DIM+128 ? bk[i-DIM] : bv[i-DIM-128]);
            bqkv[i] = v;
        }
        return;
    }
    if (blk >= 4352) {                       // pad fill: 128 blocks
        int idx = (blk - 4352) * 256 + tid;  // 0..32767
        h16x8 z8 = {};
        h16* dstb = (idx < 16384) ? kpad : vtpad;
        int i2 = idx & 16383;
        int bg = i2 >> 12, j = i2 & 4095;
        if (j < 2048) {
            size_t off;
            if (idx < 16384) {               // kpad: rows 0..127 then 2176..2303
                off = (j < 1024) ? (size_t)j*8 : (size_t)2176*HD + (size_t)(j-1024)*8;
            } else {                         // vtpad: per d, cols [0,128)+[2176,2304)
                int d = j >> 5, r = j & 31;
                off = (size_t)d*SPAD + ((r & 16) ? 2176 : 0) + (size_t)(r & 15)*8;
            }
            *(h16x8*)(dstb + (size_t)bg*KPS + off) = z8;
        }
        return;
    }
    const int tx = tid & 31, ty = tid >> 5;
    if (blk < 2048 + 1280) {
        int bid = blk - 2048;
        int n0 = (bid % 40) * 32, k0 = (bid / 40) * 32;
        const float* src; int ldn, noff; float scl;
        if (n0 < DIM)          { src = Wq; ldn = DIM; noff = n0; scl = LOG2E; }
        else if (n0 < DIM+128) { src = Wk; ldn = 128; noff = n0 - DIM; scl = 1.f; }
        else                   { src = Wv; ldn = 128; noff = n0 - DIM - 128; scl = 1.f; }
#pragma unroll
        for (int i = 0; i < 4; ++i)
            tile[ty + 8*i][tx] = src[(size_t)(k0 + ty + 8*i)*ldn + noff + tx] * scl;
        __syncthreads();
#pragma unroll
        for (int i = 0; i < 4; ++i)
            wqkvt[(size_t)(n0 + ty + 8*i)*DIM + k0 + tx] = (h16)tile[tx][ty + 8*i];
    } else {
        int bid = blk - 3328;
        int n0 = (bid % 32) * 32, k0 = (bid / 32) * 32;
#pragma unroll
        for (int i = 0; i < 4; ++i)
            tile[ty + 8*i][tx] = Wo[(size_t)(k0 + ty + 8*i)*DIM + n0 + tx];
        __syncthreads();
#pragma unroll
        for (int i = 0; i < 4; ++i)
            wot[(size_t)(n0 + ty + 8*i)*DIM + k0 + tx] = (h16)tile[tx][ty + 8*i];
    }
}

// ------------- GEMM: 128x128 tile, BK=64, 4 waves, 2-phase counted vmcnt(8) ----
// MODE 0: n-tiles 0..7 -> q [m][n]; n-tile 8 -> k_pad scatter; n-tile 9 ->
//         v transposed through LDS -> vt_pad (fused vtrans).
// MODE 1: fp32 out + bias.
template<int MODE>
__global__ __launch_bounds__(256, 2)
void gemm_kernel(const h16* __restrict__ A, const h16* __restrict__ Bt,
                 const float* __restrict__ bias,
                 h16* __restrict__ qo, h16* __restrict__ ko, h16* __restrict__ vo,
                 float* __restrict__ co, int K, int nx)
{
    __shared__ __align__(16) h16 lds[2][2][128*64];   // [buf][A/B] = 64 KB
    const int nwg = gridDim.x, bid = blockIdx.x;
    const int wg = (bid & 7) * (nwg >> 3) + (bid >> 3);   // XCD swizzle (nwg%8==0)
    const int m0 = (wg / nx) * 128, n0 = (wg % nx) * 128;
    const int tid = threadIdx.x, lane = tid & 63, wid = tid >> 6;
    const int wr = wid >> 1, wc = wid & 1;                // 2x2 waves, 64x64 each
    f32x4 acc[4][4] = {};

    auto stage = [&](int buf, int kk) {
#pragma unroll
        for (int i = 0; i < 4; ++i) {
            int slot = i*256 + tid;
            int row = slot >> 3;
            int scol = ((slot & 7) ^ (row & 7)) * 8;
            __builtin_amdgcn_global_load_lds(
                (const __attribute__((address_space(1))) void*)(A + (size_t)(m0 + row)*K + kk + scol),
                (__attribute__((address_space(3))) void*)(&lds[buf][0][slot*8]), 16, 0, 0);
        }
#pragma unroll
        for (int i = 0; i < 4; ++i) {
            int slot = i*256 + tid;
            int row = slot >> 3;
            int scol = ((slot & 7) ^ (row & 7)) * 8;
            __builtin_amdgcn_global_load_lds(
                (const __attribute__((address_space(1))) void*)(Bt + (size_t)(n0 + row)*K + kk + scol),
                (__attribute__((address_space(3))) void*)(&lds[buf][1][slot*8]), 16, 0, 0);
        }
    };
    auto compute = [&](int buf) {
#pragma unroll
        for (int k2 = 0; k2 < 2; ++k2) {
            h16x8 a[4], b[4];
#pragma unroll
            for (int mi = 0; mi < 4; ++mi) {
                int row = wr*64 + mi*16 + (lane & 15);
                int cc = (k2*4 + (lane >> 4)) ^ (row & 7);
                a[mi] = *(const h16x8*)(&lds[buf][0][row*64 + cc*8]);
            }
#pragma unroll
            for (int ni = 0; ni < 4; ++ni) {
                int row = wc*64 + ni*16 + (lane & 15);
                int cc = (k2*4 + (lane >> 4)) ^ (row & 7);
                b[ni] = *(const h16x8*)(&lds[buf][1][row*64 + cc*8]);
            }
#pragma unroll
            for (int mi = 0; mi < 4; ++mi)
#pragma unroll
                for (int ni = 0; ni < 4; ++ni)
                    acc[mi][ni] = __builtin_amdgcn_mfma_f32_16x16x32_f16(a[mi], b[ni], acc[mi][ni], 0, 0, 0);
        }
    };

    const int ns = K >> 6;
    stage(0, 0);
    int cur = 0;
    for (int i = 0; i < ns; ++i) {
        if (i < ns-1) {
            stage(cur ^ 1, (i+1) << 6);                      // 8 loads in flight
            asm volatile("s_waitcnt vmcnt(8)" ::: "memory"); // prev stage landed
        } else {
            asm volatile("s_waitcnt vmcnt(0)" ::: "memory");
        }
        __builtin_amdgcn_s_barrier();
        __builtin_amdgcn_sched_barrier(0);
        compute(cur);
        if (i < ns-1) {
            __builtin_amdgcn_s_barrier();
            __builtin_amdgcn_sched_barrier(0);
        }
        cur ^= 1;
    }

    if (MODE == 0 && n0 == DIM + 128) {
        // ---- v tile: transpose 128s x 128(g,d) through LDS -> vt_pad d-rows ----
        __syncthreads();
        h16* T = &lds[0][0][0];                            // [128][136] = 34 KB
#pragma unroll
        for (int ni = 0; ni < 4; ++ni) {
            int nrel = wc*64 + ni*16 + (lane & 15);
            float bv = bias[n0 + nrel];
#pragma unroll
            for (int mi = 0; mi < 4; ++mi) {
                int mrel = wr*64 + mi*16 + (lane >> 4)*4;
#pragma unroll
                for (int r = 0; r < 4; ++r)
                    T[nrel*136 + mrel + r] = (h16)(acc[mi][ni][r] + bv);
            }
        }
        __syncthreads();
        const int bi2 = m0 >> 11, sbase = m0 & 2047;
#pragma unroll
        for (int i = 0; i < 8; ++i) {
            int slot = i*256 + tid;                        // 128 nrel x 16 chunks
            int nrel = slot >> 4, cc = slot & 15;
            int g = nrel >> 6, d = nrel & 63;
            h16x8 val = *(const h16x8*)(T + nrel*136 + cc*8);
            *(h16x8*)(vo + ((size_t)(bi2*NKV + g))*KPS + (size_t)d*SPAD
                      + HALFW + sbase + cc*8) = val;
        }
        return;
    }

#pragma unroll
    for (int ni = 0; ni < 4; ++ni) {
        int n = n0 + wc*64 + ni*16 + (lane & 15);
        float bv = bias[n];
#pragma unroll
        for (int mi = 0; mi < 4; ++mi) {
            int mb = m0 + wr*64 + mi*16 + (lane >> 4)*4;
#pragma unroll
            for (int r = 0; r < 4; ++r) {
                int m = mb + r;
                float v = acc[mi][ni][r] + bv;
                if (MODE == 1) {
                    co[(size_t)m*DIM + n] = v;
                } else {
                    h16 hv = (h16)v;
                    if (n < DIM) {
                        qo[(size_t)m*DIM + n] = hv;
                    } else {
                        int nn = n - DIM;                  // k region (n-tile 8)
                        int bi2 = m >> 11, s = m & 2047;
                        int g = nn >> 6, d = nn & 63;
                        ko[((size_t)(bi2*NKV + g)*SPAD + s + HALFW)*HD + d] = hv;
                    }
                }
            }
        }
    }
}

// ------------- sliding-window attention (staged, branch-free padded K/V) -------
// block = (qt of 32, g, b) -> 64x2x2; 8 waves, wave = head (h = g*8 + wid).
// Ks [288][64] XOR-swizzled; Vts [64][312]; P per wave [16][296] (UNNORMALIZED;
// per-row inv applied in epilogue via __shfl(inv, qrow)).
__global__ __launch_bounds__(512)
void attn_kernel(const h16* __restrict__ qb, const h16* __restrict__ kpad,
                 const h16* __restrict__ vtpad, h16* __restrict__ ob)
{
    extern __shared__ char smem[];
    h16* Ks  = (h16*)smem;                          // 36864 B
    h16* Vts = (h16*)(smem + 36864);                // 39936 B
    h16* Ps  = (h16*)(smem + 76800);                // 75776 B (total 152576)
    const int tid = threadIdx.x, lane = tid & 63, wid = tid >> 6;
    const int qt = blockIdx.x, g = blockIdx.y, bi = blockIdx.z;
    const int s0 = qt * 32;
    const h16* Kbase = kpad  + (size_t)(bi*NKV + g)*KPS + (size_t)s0*HD;
    const h16* Vbase = vtpad + (size_t)(bi*NKV + g)*KPS + s0;

    // stage K rows (padded source: no bounds), XOR-swizzled
    for (int slot = tid; slot < KSTG*8; slot += 512) {
        int row = slot >> 3, cc = slot & 7;
        h16x8 val = *(const h16x8*)(Kbase + (size_t)row*HD + cc*8);
        *(h16x8*)(Ks + row*64 + ((cc ^ (row & 7)) * 8)) = val;
    }
    // stage Vt [64][304] (padded source: no bounds)
    for (int slot = tid; slot < 64*38; slot += 512) {
        int row = slot / 38, cc = slot - row*38;
        h16x8 val = *(const h16x8*)(Vbase + (size_t)row*SPAD + cc*8);
        *(h16x8*)(Vts + row*VSTR + cc*8) = val;
    }
    // zero own wave's P pad cols [272,288)
    h16* P = Ps + wid * 16 * PSTR;
    for (int i = lane; i < 256; i += 64)
        P[(i >> 4)*PSTR + 272 + (i & 15)] = (h16)0;
    __syncthreads();

    const int h = g*8 + wid;
    const int colbase = lane & 15;          // query (strip-local)
    const int rowbase = (lane >> 4) * 4;    // key sub-row
    const int kg = rowbase;

    for (int strip = 0; strip < 2; ++strip) {
        const int ss0 = s0 + strip*16;
        h16x8 aq[2];
#pragma unroll
        for (int c = 0; c < 2; ++c)
            aq[c] = *(const h16x8*)(qb + ((size_t)(bi*SEQ + ss0 + colbase))*DIM
                                    + h*HD + c*32 + (lane >> 4)*8);

        // scores (swapped): sc[t][r] = score(query=colbase, key=16t+kg+r)
        f32x4 sc[17];
        __builtin_amdgcn_s_setprio(1);
#pragma unroll
        for (int t = 0; t < 17; ++t) {
            f32x4 z = {0.f,0.f,0.f,0.f};
#pragma unroll
            for (int c = 0; c < 2; ++c) {
                int key = strip*16 + t*16 + colbase;
                h16x8 kf = *(const h16x8*)(Ks + key*64 + (((c*4 + (lane >> 4)) ^ (key & 7)) * 8));
                z = __builtin_amdgcn_mfma_f32_16x16x32_f16(kf, aq[c], z, 0, 0, 0);
            }
            sc[t] = z;
        }
        __builtin_amdgcn_s_setprio(0);

        // mask boundary tiles: t=0 needs key>=q, t=16 needs key<q
        float mx = -1e30f;
#pragma unroll
        for (int r = 0; r < 4; ++r) {
            float v0  = (kg + r >= colbase) ? sc[0][r]  : -1e30f;
            float v16 = (kg + r <  colbase) ? sc[16][r] : -1e30f;
            sc[0][r] = v0; sc[16][r] = v16;
            mx = fmaxf(mx, fmaxf(v0, v16));
        }
        // max3-friendly tree over tiles 1..15
#pragma unroll
        for (int t = 1; t < 16; t += 3) {
#pragma unroll
            for (int r = 0; r < 4; ++r) {
                float a = sc[t][r];
                float b = (t+1 < 16) ? sc[t+1][r] : -1e30f;
                float c2 = (t+2 < 16) ? sc[t+2][r] : -1e30f;
                mx = fmaxf(mx, fmaxf(fmaxf(a, b), c2));
            }
        }
        mx = fmaxf(mx, __shfl_xor(mx, 16));
        mx = fmaxf(mx, __shfl_xor(mx, 32));
        float sum = 0.f;
#pragma unroll
        for (int t = 0; t < 17; ++t)
#pragma unroll
            for (int r = 0; r < 4; ++r) {
                float p = exp2f(sc[t][r] - mx);   // scores pre-scaled by log2e
                sc[t][r] = p;
                sum += p;
            }
        sum += __shfl_xor(sum, 16);
        sum += __shfl_xor(sum, 32);
        float inv = 1.0f / sum;                   // per-query (colbase) inverse

        // write P UNNORMALIZED (p <= 1, h16-safe)
#pragma unroll
        for (int t = 0; t < 17; ++t) {
            h16x4 pk = { (h16)sc[t][0], (h16)sc[t][1],
                         (h16)sc[t][2], (h16)sc[t][3] };
            *(h16x4*)(P + colbase*PSTR + t*16 + kg) = pk;
        }

        // PV: (16x288) x (288x64) from LDS
        f32x4 ao[4] = {};
        __builtin_amdgcn_s_setprio(1);
#pragma unroll
        for (int c = 0; c < 9; ++c) {
            h16x8 pa = *(const h16x8*)(P + colbase*PSTR + c*32 + (lane >> 4)*8);
            int vcol = strip*16 + c*32 + (lane >> 4)*8;
#pragma unroll
            for (int t2 = 0; t2 < 4; ++t2) {
                h16x8 vb = *(const h16x8*)(Vts + (t2*16 + colbase)*VSTR + vcol);
                ao[t2] = __builtin_amdgcn_mfma_f32_16x16x32_f16(pa, vb, ao[t2], 0, 0, 0);
            }
        }
        __builtin_amdgcn_s_setprio(0);

        // epilogue: normalize by the OWNING query's inv (lane qrow has colbase=qrow)
#pragma unroll
        for (int r = 0; r < 4; ++r) {
            int qrow = rowbase + r;
            float iq = __shfl(inv, qrow);
            size_t rowoff = ((size_t)(bi*SEQ + ss0 + qrow))*DIM + h*HD;
#pragma unroll
            for (int t2 = 0; t2 < 4; ++t2)
                ob[rowoff + t2*16 + colbase] = (h16)(ao[t2][r] * iq);
        }
    }
}

extern "C" void kernel_launch(void* const* d_in, const int* in_sizes, int n_in,
                              void* d_out, int out_size, void* d_ws, size_t ws_size,
                              hipStream_t stream)
{
    const float* x  = (const float*)d_in[0];
    const float* Wq = (const float*)d_in[1];
    const float* bq = (const float*)d_in[2];
    const float* Wk = (const float*)d_in[3];
    const float* bk = (const float*)d_in[4];
    const float* Wv = (const float*)d_in[5];
    const float* bv = (const float*)d_in[6];
    const float* Wo = (const float*)d_in[7];
    const float* bo = (const float*)d_in[8];
    float* out = (float*)d_out;
    char* ws = (char*)d_ws;

    h16*   xh    = (h16*)(ws);                 //  x fp16 [4096][1024]
    h16*   wqkvt = (h16*)(ws + 8388608);       //  Wqkv^T [1280][1024]
    h16*   wot   = (h16*)(ws + 11010048);      //  Wo^T [1024][1024]
    float* bqkv  = (float*)(ws + 13107200);
    h16*   q_b   = (h16*)(ws + 13112320);      //  q [4096][1024]
    h16*   k_pad = (h16*)(ws + 21500928);      //  k_pad [b][g][2304][64]
    h16*   vt_pad= (h16*)(ws + 22680576);      //  vt_pad [b][g][64][2304]
    h16*   att_b = (h16*)(ws + 23860224);      //  attn out [4096][1024]

    preprocess_kernel<<<4480, 256, 0, stream>>>(x, bq, bk, bv, Wq, Wk, Wv, Wo,
                                                xh, bqkv, wqkvt, wot, k_pad, vt_pad);
    gemm_kernel<0><<<320, 256, 0, stream>>>(xh, wqkvt, bqkv,
                                            q_b, k_pad, vt_pad, nullptr, DIM, 10);
    hipFuncSetAttribute((const void*)attn_kernel,
                        hipFuncAttributeMaxDynamicSharedMemorySize, 152576);
    attn_kernel<<<dim3(64, 2, 2), 512, 152576, stream>>>(q_b, k_pad, vt_pad, att_b);
    gemm_kernel<1><<<256, 256, 0, stream>>>(att_b, wot, bo,
                                            nullptr, nullptr, nullptr, out, DIM, 8);
}

// Round 24
// 63.480 us; speedup vs baseline: 1.0449x; 1.0053x over previous
//
#include <hip/hip_runtime.h>
#include <hip/hip_fp16.h>

typedef _Float16 h16;
typedef __attribute__((ext_vector_type(4))) _Float16 h16x4;
typedef __attribute__((ext_vector_type(8))) _Float16 h16x8;
typedef __attribute__((ext_vector_type(4))) float f32x4;

#define DIM   1024
#define SEQ   2048
#define NKV   2
#define HD    64
#define HALFW 128
#define NQKV  1280
#define SPAD  2304            // padded seq: 128 + 2048 + 128
#define KPS   (SPAD*HD)       // 147456 h16 per [b][g] slab
#define KSTG  288             // staged key rows per 32-query block
#define VSTR  312             // Vts row stride (2-way-conflict-free)
#define PSTR  296             // P row stride (2-way-conflict-free)
#define LOG2E 1.4426950408889634f

// ---------------- fused preprocess ----------------
// [0,2048): x fp32->fp16 (+bias concat, bq*log2e)
// [2048,3328): Wq|Wk|Wv transpose -> wqkvt (Wq part * log2e)
// [3328,4352): Wo transpose -> wot
// [4352,4480): zero-fill pad regions of k_pad AND vt_pad
__global__ void preprocess_kernel(const float* __restrict__ x,
                                  const float* __restrict__ bq,
                                  const float* __restrict__ bk,
                                  const float* __restrict__ bv,
                                  const float* __restrict__ Wq,
                                  const float* __restrict__ Wk,
                                  const float* __restrict__ Wv,
                                  const float* __restrict__ Wo,
                                  h16* __restrict__ xh, float* __restrict__ bqkv,
                                  h16* __restrict__ wqkvt, h16* __restrict__ wot,
                                  h16* __restrict__ kpad, h16* __restrict__ vtpad)
{
    __shared__ float tile[32][33];
    const int tid = threadIdx.x;
    const int blk = blockIdx.x;
    if (blk < 2048) {
        int i = blk * 256 + tid;
        size_t base = (size_t)i * 8;
        float4 a = *(const float4*)(x + base);
        float4 b = *(const float4*)(x + base + 4);
        h16x8 o = { (h16)a.x,(h16)a.y,(h16)a.z,(h16)a.w,
                    (h16)b.x,(h16)b.y,(h16)b.z,(h16)b.w };
        *(h16x8*)(xh + base) = o;
        if (i < NQKV) {
            float v = (i < DIM) ? bq[i] * LOG2E
                                : (i < DIM+128 ? bk[i-DIM] : bv[i-DIM-128]);
            bqkv[i] = v;
        }
        return;
    }
    if (blk >= 4352) {                       // pad fill: 128 blocks
        int idx = (blk - 4352) * 256 + tid;  // 0..32767
        h16x8 z8 = {};
        h16* dstb = (idx < 16384) ? kpad : vtpad;
        int i2 = idx & 16383;
        int bg = i2 >> 12, j = i2 & 4095;
        if (j < 2048) {
            size_t off;
            if (idx < 16384) {               // kpad: rows 0..127 then 2176..2303
                off = (j < 1024) ? (size_t)j*8 : (size_t)2176*HD + (size_t)(j-1024)*8;
            } else {                         // vtpad: per d, cols [0,128)+[2176,2304)
                int d = j >> 5, r = j & 31;
                off = (size_t)d*SPAD + ((r & 16) ? 2176 : 0) + (size_t)(r & 15)*8;
            }
            *(h16x8*)(dstb + (size_t)bg*KPS + off) = z8;
        }
        return;
    }
    const int tx = tid & 31, ty = tid >> 5;
    if (blk < 2048 + 1280) {
        int bid = blk - 2048;
        int n0 = (bid % 40) * 32, k0 = (bid / 40) * 32;
        const float* src; int ldn, noff; float scl;
        if (n0 < DIM)          { src = Wq; ldn = DIM; noff = n0; scl = LOG2E; }
        else if (n0 < DIM+128) { src = Wk; ldn = 128; noff = n0 - DIM; scl = 1.f; }
        else                   { src = Wv; ldn = 128; noff = n0 - DIM - 128; scl = 1.f; }
#pragma unroll
        for (int i = 0; i < 4; ++i)
            tile[ty + 8*i][tx] = src[(size_t)(k0 + ty + 8*i)*ldn + noff + tx] * scl;
        __syncthreads();
#pragma unroll
        for (int i = 0; i < 4; ++i)
            wqkvt[(size_t)(n0 + ty + 8*i)*DIM + k0 + tx] = (h16)tile[tx][ty + 8*i];
    } else {
        int bid = blk - 3328;
        int n0 = (bid % 32) * 32, k0 = (bid / 32) * 32;
#pragma unroll
        for (int i = 0; i < 4; ++i)
            tile[ty + 8*i][tx] = Wo[(size_t)(k0 + ty + 8*i)*DIM + n0 + tx];
        __syncthreads();
#pragma unroll
        for (int i = 0; i < 4; ++i)
            wot[(size_t)(n0 + ty + 8*i)*DIM + k0 + tx] = (h16)tile[tx][ty + 8*i];
    }
}

// ------------- GEMM: 128x128 tile, BK=64, 4 waves, 2-phase counted vmcnt(8) ----
// MODE 0: n-tiles 0..7 -> q [m][n]; n-tile 8 -> k_pad scatter; n-tile 9 ->
//         v transposed through LDS -> vt_pad (fused vtrans).
// MODE 1: fp32 out + bias.
template<int MODE>
__global__ __launch_bounds__(256, 2)
void gemm_kernel(const h16* __restrict__ A, const h16* __restrict__ Bt,
                 const float* __restrict__ bias,
                 h16* __restrict__ qo, h16* __restrict__ ko, h16* __restrict__ vo,
                 float* __restrict__ co, int K, int nx)
{
    __shared__ __align__(16) h16 lds[2][2][128*64];   // [buf][A/B] = 64 KB
    const int nwg = gridDim.x, bid = blockIdx.x;
    const int wg = (bid & 7) * (nwg >> 3) + (bid >> 3);   // XCD swizzle (nwg%8==0)
    const int m0 = (wg / nx) * 128, n0 = (wg % nx) * 128;
    const int tid = threadIdx.x, lane = tid & 63, wid = tid >> 6;
    const int wr = wid >> 1, wc = wid & 1;                // 2x2 waves, 64x64 each
    f32x4 acc[4][4] = {};

    auto stage = [&](int buf, int kk) {
#pragma unroll
        for (int i = 0; i < 4; ++i) {
            int slot = i*256 + tid;
            int row = slot >> 3;
            int scol = ((slot & 7) ^ (row & 7)) * 8;
            __builtin_amdgcn_global_load_lds(
                (const __attribute__((address_space(1))) void*)(A + (size_t)(m0 + row)*K + kk + scol),
                (__attribute__((address_space(3))) void*)(&lds[buf][0][slot*8]), 16, 0, 0);
        }
#pragma unroll
        for (int i = 0; i < 4; ++i) {
            int slot = i*256 + tid;
            int row = slot >> 3;
            int scol = ((slot & 7) ^ (row & 7)) * 8;
            __builtin_amdgcn_global_load_lds(
                (const __attribute__((address_space(1))) void*)(Bt + (size_t)(n0 + row)*K + kk + scol),
                (__attribute__((address_space(3))) void*)(&lds[buf][1][slot*8]), 16, 0, 0);
        }
    };
    auto compute = [&](int buf) {
#pragma unroll
        for (int k2 = 0; k2 < 2; ++k2) {
            h16x8 a[4], b[4];
#pragma unroll
            for (int mi = 0; mi < 4; ++mi) {
                int row = wr*64 + mi*16 + (lane & 15);
                int cc = (k2*4 + (lane >> 4)) ^ (row & 7);
                a[mi] = *(const h16x8*)(&lds[buf][0][row*64 + cc*8]);
            }
#pragma unroll
            for (int ni = 0; ni < 4; ++ni) {
                int row = wc*64 + ni*16 + (lane & 15);
                int cc = (k2*4 + (lane >> 4)) ^ (row & 7);
                b[ni] = *(const h16x8*)(&lds[buf][1][row*64 + cc*8]);
            }
#pragma unroll
            for (int mi = 0; mi < 4; ++mi)
#pragma unroll
                for (int ni = 0; ni < 4; ++ni)
                    acc[mi][ni] = __builtin_amdgcn_mfma_f32_16x16x32_f16(a[mi], b[ni], acc[mi][ni], 0, 0, 0);
        }
    };

    const int ns = K >> 6;
    stage(0, 0);
    int cur = 0;
    for (int i = 0; i < ns; ++i) {
        if (i < ns-1) {
            stage(cur ^ 1, (i+1) << 6);                      // 8 loads in flight
            asm volatile("s_waitcnt vmcnt(8)" ::: "memory"); // prev stage landed
        } else {
            asm volatile("s_waitcnt vmcnt(0)" ::: "memory");
        }
        __builtin_amdgcn_s_barrier();
        __builtin_amdgcn_sched_barrier(0);
        compute(cur);
        if (i < ns-1) {
            __builtin_amdgcn_s_barrier();
            __builtin_amdgcn_sched_barrier(0);
        }
        cur ^= 1;
    }

    if (MODE == 0 && n0 == DIM + 128) {
        // ---- v tile: transpose 128s x 128(g,d) through LDS -> vt_pad d-rows ----
        __syncthreads();
        h16* T = &lds[0][0][0];                            // [128][136] = 34 KB
#pragma unroll
        for (int ni = 0; ni < 4; ++ni) {
            int nrel = wc*64 + ni*16 + (lane & 15);
            float bv = bias[n0 + nrel];
#pragma unroll
            for (int mi = 0; mi < 4; ++mi) {
                int mrel = wr*64 + mi*16 + (lane >> 4)*4;
#pragma unroll
                for (int r = 0; r < 4; ++r)
                    T[nrel*136 + mrel + r] = (h16)(acc[mi][ni][r] + bv);
            }
        }
        __syncthreads();
        const int bi2 = m0 >> 11, sbase = m0 & 2047;
#pragma unroll
        for (int i = 0; i < 8; ++i) {
            int slot = i*256 + tid;                        // 128 nrel x 16 chunks
            int nrel = slot >> 4, cc = slot & 15;
            int g = nrel >> 6, d = nrel & 63;
            h16x8 val = *(const h16x8*)(T + nrel*136 + cc*8);
            *(h16x8*)(vo + ((size_t)(bi2*NKV + g))*KPS + (size_t)d*SPAD
                      + HALFW + sbase + cc*8) = val;
        }
        return;
    }

#pragma unroll
    for (int ni = 0; ni < 4; ++ni) {
        int n = n0 + wc*64 + ni*16 + (lane & 15);
        float bv = bias[n];
#pragma unroll
        for (int mi = 0; mi < 4; ++mi) {
            int mb = m0 + wr*64 + mi*16 + (lane >> 4)*4;
#pragma unroll
            for (int r = 0; r < 4; ++r) {
                int m = mb + r;
                float v = acc[mi][ni][r] + bv;
                if (MODE == 1) {
                    co[(size_t)m*DIM + n] = v;
                } else {
                    h16 hv = (h16)v;
                    if (n < DIM) {
                        qo[(size_t)m*DIM + n] = hv;
                    } else {
                        int nn = n - DIM;                  // k region (n-tile 8)
                        int bi2 = m >> 11, s = m & 2047;
                        int g = nn >> 6, d = nn & 63;
                        ko[((size_t)(bi2*NKV + g)*SPAD + s + HALFW)*HD + d] = hv;
                    }
                }
            }
        }
    }
}

// ------------- sliding-window attention (staged, branch-free padded K/V) -------
// block = (qt of 32, g, b) -> 64x2x2; 8 waves, wave = head (h = g*8 + wid).
// Ks [288][64] XOR-swizzled; Vts [64][312]; P per wave [16][296] (UNNORMALIZED;
// per-row inv applied in epilogue via __shfl(inv, qrow)).
__global__ __launch_bounds__(512)
void attn_kernel(const h16* __restrict__ qb, const h16* __restrict__ kpad,
                 const h16* __restrict__ vtpad, h16* __restrict__ ob)
{
    extern __shared__ char smem[];
    h16* Ks  = (h16*)smem;                          // 36864 B
    h16* Vts = (h16*)(smem + 36864);                // 39936 B
    h16* Ps  = (h16*)(smem + 76800);                // 75776 B (total 152576)
    const int tid = threadIdx.x, lane = tid & 63, wid = tid >> 6;
    const int qt = blockIdx.x, g = blockIdx.y, bi = blockIdx.z;
    const int s0 = qt * 32;
    const h16* Kbase = kpad  + (size_t)(bi*NKV + g)*KPS + (size_t)s0*HD;
    const h16* Vbase = vtpad + (size_t)(bi*NKV + g)*KPS + s0;

    // stage K rows (padded source: no bounds), XOR-swizzled
    for (int slot = tid; slot < KSTG*8; slot += 512) {
        int row = slot >> 3, cc = slot & 7;
        h16x8 val = *(const h16x8*)(Kbase + (size_t)row*HD + cc*8);
        *(h16x8*)(Ks + row*64 + ((cc ^ (row & 7)) * 8)) = val;
    }
    // stage Vt [64][304] (padded source: no bounds)
    for (int slot = tid; slot < 64*38; slot += 512) {
        int row = slot / 38, cc = slot - row*38;
        h16x8 val = *(const h16x8*)(Vbase + (size_t)row*SPAD + cc*8);
        *(h16x8*)(Vts + row*VSTR + cc*8) = val;
    }
    // zero own wave's P pad cols [272,288)
    h16* P = Ps + wid * 16 * PSTR;
    for (int i = lane; i < 256; i += 64)
        P[(i >> 4)*PSTR + 272 + (i & 15)] = (h16)0;
    __syncthreads();

    const int h = g*8 + wid;
    const int colbase = lane & 15;          // query (strip-local)
    const int rowbase = (lane >> 4) * 4;    // key sub-row
    const int kg = rowbase;

    for (int strip = 0; strip < 2; ++strip) {
        const int ss0 = s0 + strip*16;
        h16x8 aq[2];
#pragma unroll
        for (int c = 0; c < 2; ++c)
            aq[c] = *(const h16x8*)(qb + ((size_t)(bi*SEQ + ss0 + colbase))*DIM
                                    + h*HD + c*32 + (lane >> 4)*8);

        // scores (swapped): sc[t][r] = score(query=colbase, key=16t+kg+r)
        f32x4 sc[17];
        __builtin_amdgcn_s_setprio(1);
#pragma unroll
        for (int t = 0; t < 17; ++t) {
            f32x4 z = {0.f,0.f,0.f,0.f};
#pragma unroll
            for (int c = 0; c < 2; ++c) {
                int key = strip*16 + t*16 + colbase;
                h16x8 kf = *(const h16x8*)(Ks + key*64 + (((c*4 + (lane >> 4)) ^ (key & 7)) * 8));
                z = __builtin_amdgcn_mfma_f32_16x16x32_f16(kf, aq[c], z, 0, 0, 0);
            }
            sc[t] = z;
        }
        __builtin_amdgcn_s_setprio(0);

        // mask boundary tiles: t=0 needs key>=q, t=16 needs key<q
        float mx = -1e30f;
#pragma unroll
        for (int r = 0; r < 4; ++r) {
            float v0  = (kg + r >= colbase) ? sc[0][r]  : -1e30f;
            float v16 = (kg + r <  colbase) ? sc[16][r] : -1e30f;
            sc[0][r] = v0; sc[16][r] = v16;
            mx = fmaxf(mx, fmaxf(v0, v16));
        }
        // max3-friendly tree over tiles 1..15
#pragma unroll
        for (int t = 1; t < 16; t += 3) {
#pragma unroll
            for (int r = 0; r < 4; ++r) {
                float a = sc[t][r];
                float b = (t+1 < 16) ? sc[t+1][r] : -1e30f;
                float c2 = (t+2 < 16) ? sc[t+2][r] : -1e30f;
                mx = fmaxf(mx, fmaxf(fmaxf(a, b), c2));
            }
        }
        mx = fmaxf(mx, __shfl_xor(mx, 16));
        mx = fmaxf(mx, __shfl_xor(mx, 32));
        float sum = 0.f;
#pragma unroll
        for (int t = 0; t < 17; ++t)
#pragma unroll
            for (int r = 0; r < 4; ++r) {
                float p = exp2f(sc[t][r] - mx);   // scores pre-scaled by log2e
                sc[t][r] = p;
                sum += p;
            }
        sum += __shfl_xor(sum, 16);
        sum += __shfl_xor(sum, 32);
        float inv = 1.0f / sum;                   // per-query (colbase) inverse

        // write P UNNORMALIZED (p <= 1, h16-safe)
#pragma unroll
        for (int t = 0; t < 17; ++t) {
            h16x4 pk = { (h16)sc[t][0], (h16)sc[t][1],
                         (h16)sc[t][2], (h16)sc[t][3] };
            *(h16x4*)(P + colbase*PSTR + t*16 + kg) = pk;
        }

        // PV: (16x288) x (288x64) from LDS
        f32x4 ao[4] = {};
        __builtin_amdgcn_s_setprio(1);
#pragma unroll
        for (int c = 0; c < 9; ++c) {
            h16x8 pa = *(const h16x8*)(P + colbase*PSTR + c*32 + (lane >> 4)*8);
            int vcol = strip*16 + c*32 + (lane >> 4)*8;
#pragma unroll
            for (int t2 = 0; t2 < 4; ++t2) {
                h16x8 vb = *(const h16x8*)(Vts + (t2*16 + colbase)*VSTR + vcol);
                ao[t2] = __builtin_amdgcn_mfma_f32_16x16x32_f16(pa, vb, ao[t2], 0, 0, 0);
            }
        }
        __builtin_amdgcn_s_setprio(0);

        // epilogue: normalize by the OWNING query's inv (lane qrow has colbase=qrow)
#pragma unroll
        for (int r = 0; r < 4; ++r) {
            int qrow = rowbase + r;
            float iq = __shfl(inv, qrow);
            size_t rowoff = ((size_t)(bi*SEQ + ss0 + qrow))*DIM + h*HD;
#pragma unroll
            for (int t2 = 0; t2 < 4; ++t2)
                ob[rowoff + t2*16 + colbase] = (h16)(ao[t2][r] * iq);
        }
    }
}

extern "C" void kernel_launch(void* const* d_in, const int* in_sizes, int n_in,
                              void* d_out, int out_size, void* d_ws, size_t ws_size,
                              hipStream_t stream)
{
    const float* x  = (const float*)d_in[0];
    const float* Wq = (const float*)d_in[1];
    const float* bq = (const float*)d_in[2];
    const float* Wk = (const float*)d_in[3];
    const float* bk = (const float*)d_in[4];
    const float* Wv = (const float*)d_in[5];
    const float* bv = (const float*)d_in[6];
    const float* Wo = (const float*)d_in[7];
    const float* bo = (const float*)d_in[8];
    float* out = (float*)d_out;
    char* ws = (char*)d_ws;

    h16*   xh    = (h16*)(ws);                 //  x fp16 [4096][1024]
    h16*   wqkvt = (h16*)(ws + 8388608);       //  Wqkv^T [1280][1024]
    h16*   wot   = (h16*)(ws + 11010048);      //  Wo^T [1024][1024]
    float* bqkv  = (float*)(ws + 13107200);
    h16*   q_b   = (h16*)(ws + 13112320);      //  q [4096][1024]
    h16*   k_pad = (h16*)(ws + 21500928);      //  k_pad [b][g][2304][64]
    h16*   vt_pad= (h16*)(ws + 22680576);      //  vt_pad [b][g][64][2304]
    h16*   att_b = (h16*)(ws + 23860224);      //  attn out [4096][1024]

    preprocess_kernel<<<4480, 256, 0, stream>>>(x, bq, bk, bv, Wq, Wk, Wv, Wo,
                                                xh, bqkv, wqkvt, wot, k_pad, vt_pad);
    gemm_kernel<0><<<320, 256, 0, stream>>>(xh, wqkvt, bqkv,
                                            q_b, k_pad, vt_pad, nullptr, DIM, 10);
    hipFuncSetAttribute((const void*)attn_kernel,
                        hipFuncAttributeMaxDynamicSharedMemorySize, 152576);
    attn_kernel<<<dim3(64, 2, 2), 512, 152576, stream>>>(q_b, k_pad, vt_pad, att_b);
    gemm_kernel<1><<<256, 256, 0, stream>>>(att_b, wot, bo,
                                            nullptr, nullptr, nullptr, out, DIM, 8);
}